// Round 4
// baseline (2709.493 us; speedup 1.0000x reference)
//
#include <hip/hip_runtime.h>

// Sinkhorn EMD, B=8, N=2048, eps=0.005, 50 iters.
// Persistent kernel, 256 blocks x 1024 threads (1 block/CU, co-residency
// guaranteed), hand-rolled per-batch monotonic barriers (validated R3).
// This round: (1) both point sets persist in LDS all 100 passes; per-pass
// staging only rewrites the potential column a_j = pot/K - |g|^2/K into
// sjall[.].w (|g|^2 rebuilt from G = 2g/K). (2) column-split wave pairs:
// wave w in [0,8) and w+8 share 8 rows, each covers half the cols (16
// trips of ds_read_b128), partials merged through a small LDS array.
// Passes 0..5: exact online-rescale LSE. Passes 6..99: fixed-shift
// M = row's previous log-sum (1 exp/elem), clamp +100, floored sum.

#define BB 8
#define NN 2048
#define NPASS 100
#define ONLINE_PASSES 6
#define RPW 8
#define GRID_BLOCKS 256
#define TPB 1024

constexpr float EPSV = 0.005f;
constexpr float KS   = EPSV * 0.69314718055994531f; // eps*ln2
constexpr float INVK = 1.0f / KS;
constexpr float C1V  = -EPSV * 7.6246189861593985f; // eps*log(1/2048)
constexpr float KQ4  = KS * 0.25f;        // |g|^2/K   = KQ4 * |G|^2
constexpr float K2Q  = KS * KS * 0.25f;   // |g|^2     = K2Q * |G|^2
constexpr float TWOI = 2.0f * INVK;       // G = TWOI * g

__device__ __forceinline__ float fexp2(float x) { return __builtin_amdgcn_exp2f(x); }
__device__ __forceinline__ float flog2(float x) { return __builtin_amdgcn_logf(x); }

// Monotonic-counter barrier (validated R3): arrive once, wait ctr>=target.
__device__ __forceinline__ void barrier_sync(int* ctr, int target) {
    __syncthreads();
    if (threadIdx.x == 0) {
        __threadfence();
        __hip_atomic_fetch_add(ctr, 1, __ATOMIC_ACQ_REL, __HIP_MEMORY_SCOPE_AGENT);
        while (__hip_atomic_load(ctr, __ATOMIC_ACQUIRE, __HIP_MEMORY_SCOPE_AGENT) < target) {
            __builtin_amdgcn_s_sleep(2);
        }
        __threadfence();
    }
    __syncthreads();
}

__global__ void __launch_bounds__(TPB, 4) emd_persist(
    const float* __restrict__ preds, const float* __restrict__ gts,
    float* __restrict__ fpot, float* __restrict__ gpot,
    float* __restrict__ partials, int* __restrict__ bctr, int* __restrict__ gctr,
    float* __restrict__ out)
{
    __shared__ float4 sjall[2 * NN];   // side 0 = gts, side 1 = preds; {Gx,Gy,Gz,a}
    __shared__ float  spartS[64];      // [pair][row] partial s
    __shared__ float  spartM[64];      // [pair][row] partial m (online path)
    __shared__ float  wred[16];

    const int blk  = blockIdx.x;
    const int b    = blk >> 5;                 // 32 blocks per batch
    const int rb   = blk & 31;
    const int wave = threadIdx.x >> 6;
    const int lane = threadIdx.x & 63;
    const int pair = wave & 7;
    const int half = wave >> 3;                // 0: cols 0..1023, 1: 1024..2047
    const int row0 = rb * 64 + pair * RPW;     // 64 rows per block
    const int cb   = half << 10;               // column base for this wave

    const float* pb  = preds + (size_t)b * NN * 3;
    const float* gbp = gts   + (size_t)b * NN * 3;
    float* fb = fpot + (size_t)b * NN;
    float* gb = gpot + (size_t)b * NN;
    int*   bar = bctr + b * 32;

    // one-time staging of both point sets as G = 2g/K (w filled per pass)
    for (int t = threadIdx.x; t < NN; t += TPB) {
        float gx = gbp[3*t], gy = gbp[3*t+1], gz = gbp[3*t+2];
        sjall[t]      = make_float4(gx*TWOI, gy*TWOI, gz*TWOI, 0.f);
        float qx = pb[3*t],  qy = pb[3*t+1],  qz = pb[3*t+2];
        sjall[NN + t] = make_float4(qx*TWOI, qy*TWOI, qz*TWOI, 0.f);
    }

#pragma unroll 1
    for (int pass = 0; pass < NPASS; ++pass) {
        const int odd = pass & 1;
        const float* rpts = odd ? gbp : pb;
        const float* pin  = odd ? fb  : gb;
        float*       pout = odd ? gb  : fb;
        const int    sjo  = odd ? NN  : 0;     // cols: even->gts(0), odd->preds(NN)

        // per-pass staging: only the potential column a_j
        for (int t = threadIdx.x; t < NN; t += TPB) {
            float4 d = sjall[sjo + t];
            float n2k = KQ4 * (d.x*d.x + d.y*d.y + d.z*d.z);  // |g|^2/K
            sjall[sjo + t].w = fmaf(pin[t], INVK, -n2k);
        }

        // row setup (L1-resident after first passes) — overlaps the sync
        float px[RPW], py[RPW], pz[RPW], pn[RPW], M[RPW], s[RPW];
#pragma unroll
        for (int r = 0; r < RPW; ++r) {
            int i = row0 + r;
            px[r] = rpts[3*i]; py[r] = rpts[3*i+1]; pz[r] = rpts[3*i+2];
            pn[r] = px[r]*px[r] + py[r]*py[r] + pz[r]*pz[r];
            s[r]  = 0.f;
        }
        if (pass >= ONLINE_PASSES) {
#pragma unroll
            for (int r = 0; r < RPW; ++r) {
                float prev = pout[row0 + r];       // own block wrote it last round
                M[r] = (C1V + pn[r] - prev) * INVK;
            }
        } else {
#pragma unroll
            for (int r = 0; r < RPW; ++r) M[r] = -1e30f;
        }
        __syncthreads();

        if (pass < ONLINE_PASSES) {
            // exact branchless online-rescale (2 exp/elem)
            float m[RPW];
#pragma unroll
            for (int r = 0; r < RPW; ++r) m[r] = -1e30f;
#pragma unroll 4
            for (int c = 0; c < 16; ++c) {
                float4 d = sjall[sjo + cb + c*64 + lane];
#pragma unroll
                for (int r = 0; r < RPW; ++r) {
                    float x  = fmaf(px[r], d.x, fmaf(py[r], d.y, fmaf(pz[r], d.z, d.w)));
                    float mn = fmaxf(m[r], x);
                    s[r] = fmaf(s[r], fexp2(m[r]-mn), fexp2(x-mn));
                    m[r] = mn;
                }
            }
            // lane butterfly LSE-merge
#pragma unroll
            for (int r = 0; r < RPW; ++r) {
                float mm = m[r], ss = s[r];
                for (int off = 1; off < 64; off <<= 1) {
                    float mo = __shfl_xor(mm, off, 64);
                    float so = __shfl_xor(ss, off, 64);
                    float mn = fmaxf(mm, mo);
                    ss = fmaf(ss, fexp2(mm-mn), so * fexp2(mo-mn));
                    mm = mn;
                }
                m[r] = mm; s[r] = ss;
            }
            if (half == 0 && lane == 0) {
#pragma unroll
                for (int r = 0; r < RPW; ++r) {
                    spartM[pair*8 + r] = m[r];
                    spartS[pair*8 + r] = s[r];
                }
            }
            __syncthreads();
            if (half == 1 && lane == 0) {
#pragma unroll
                for (int r = 0; r < RPW; ++r) {
                    float mo = spartM[pair*8 + r], so = spartS[pair*8 + r];
                    float mn = fmaxf(m[r], mo);
                    float st = fmaf(s[r], fexp2(m[r]-mn), so * fexp2(mo-mn));
                    pout[row0+r] = C1V + pn[r] - KS * (mn + flog2(fmaxf(st, 1e-37f)));
                }
            }
        } else {
            // fixed-shift (1 exp/elem), M identical in both pair halves
#pragma unroll 4
            for (int c = 0; c < 16; ++c) {
                float4 d = sjall[sjo + cb + c*64 + lane];
#pragma unroll
                for (int r = 0; r < RPW; ++r) {
                    float x = fmaf(px[r], d.x, fmaf(py[r], d.y, fmaf(pz[r], d.z, d.w)));
                    s[r] += fexp2(fminf(x - M[r], 100.f));
                }
            }
#pragma unroll
            for (int r = 0; r < RPW; ++r) {
                float ss = s[r];
                for (int off = 1; off < 64; off <<= 1) ss += __shfl_xor(ss, off, 64);
                s[r] = ss;
            }
            if (half == 0 && lane == 0) {
#pragma unroll
                for (int r = 0; r < RPW; ++r) spartS[pair*8 + r] = s[r];
            }
            __syncthreads();
            if (half == 1 && lane == 0) {
#pragma unroll
                for (int r = 0; r < RPW; ++r) {
                    float st = s[r] + spartS[pair*8 + r];
                    pout[row0+r] = C1V + pn[r] - KS * (M[r] + flog2(fmaxf(st, 1e-37f)));
                }
            }
        }
        barrier_sync(bar, 32 * (pass + 1));
    }

    // ---- dis: sum P*C over cols = gts with final g potential ----
    for (int t = threadIdx.x; t < NN; t += TPB) {
        float4 d = sjall[t];
        float n2k = KQ4 * (d.x*d.x + d.y*d.y + d.z*d.z);
        sjall[t].w = fmaf(gb[t], INVK, -n2k);
    }
    float px[RPW], py[RPW], pz[RPW], pn[RPW], bb2[RPW], acc[RPW];
#pragma unroll
    for (int r = 0; r < RPW; ++r) {
        int i = row0 + r;
        px[r] = pb[3*i]; py[r] = pb[3*i+1]; pz[r] = pb[3*i+2];
        pn[r] = px[r]*px[r] + py[r]*py[r] + pz[r]*pz[r];
        bb2[r] = (fb[i] - pn[r]) * INVK;
        acc[r] = 0.f;
    }
    __syncthreads();
#pragma unroll 4
    for (int c = 0; c < 16; ++c) {
        float4 d = sjall[cb + c*64 + lane];
        float gn = K2Q * (d.x*d.x + d.y*d.y + d.z*d.z);   // |g|^2
#pragma unroll
        for (int r = 0; r < RPW; ++r) {
            float dot = fmaf(px[r], d.x, fmaf(py[r], d.y, pz[r]*d.z));
            float y   = dot + d.w + bb2[r];               // log2 P
            float e   = fexp2(fminf(y, 80.f));
            float Cc  = fmaf(-KS, dot, pn[r] + gn);
            acc[r] = fmaf(e, Cc, acc[r]);
        }
    }
    float tot = 0.f;
#pragma unroll
    for (int r = 0; r < RPW; ++r) tot += acc[r];
    for (int off = 1; off < 64; off <<= 1) tot += __shfl_xor(tot, off, 64);
    if (lane == 0) wred[wave] = tot;
    __syncthreads();
    if (threadIdx.x == 0) {
        float v = 0.f;
        for (int w = 0; w < 16; ++w) v += wred[w];
        partials[blk] = v;
    }

    barrier_sync(gctr, GRID_BLOCKS);

    if (blk == 0) {
        float v = (threadIdx.x < GRID_BLOCKS) ? partials[threadIdx.x] : 0.f;
        for (int off = 1; off < 64; off <<= 1) v += __shfl_xor(v, off, 64);
        if (lane == 0) wred[wave] = v;
        __syncthreads();
        if (threadIdx.x == 0) {
            float t2 = 0.f;
            for (int w = 0; w < 16; ++w) t2 += wred[w];
            out[0] = t2 * (1.0f / BB);
        }
    }
}

extern "C" void kernel_launch(void* const* d_in, const int* in_sizes, int n_in,
                              void* d_out, int out_size, void* d_ws, size_t ws_size,
                              hipStream_t stream) {
    const float* preds = (const float*)d_in[0];
    const float* gts   = (const float*)d_in[1];
    float* fp       = (float*)d_ws;                   // [B*N]
    float* gp       = fp + BB * NN;                   // [B*N]
    float* partials = gp + BB * NN;                   // [256]
    int*   bctr     = (int*)(partials + GRID_BLOCKS); // 8 x 32 ints
    int*   gctr     = bctr + BB * 32;                 // [32]
    float* out      = (float*)d_out;

    size_t zbytes = (size_t)(2 * BB * NN + GRID_BLOCKS) * sizeof(float)
                  + (size_t)(BB * 32 + 32) * sizeof(int);
    hipMemsetAsync(d_ws, 0, zbytes, stream);

    emd_persist<<<dim3(GRID_BLOCKS), dim3(TPB), 0, stream>>>(
        preds, gts, fp, gp, partials, bctr, gctr, out);
}